// Round 9
// baseline (165.772 us; speedup 1.0000x reference)
//
#include <hip/hip_runtime.h>
#include <math.h>

#define BATCH 8
#define DIMD  512
#define NTOK  1024
#define NH    8
#define CQKV  640
#define DOUT  512

typedef __attribute__((ext_vector_type(8))) short short8;
typedef __attribute__((ext_vector_type(4))) short short4v;
typedef __attribute__((ext_vector_type(4))) float f32x4;

__device__ __forceinline__ short bf16rn(float x) {
    unsigned u = __float_as_uint(x);
    u += 0x7FFF + ((u >> 16) & 1);
    return (short)(u >> 16);
}
__device__ __forceinline__ float bf16tof(short s) {
    return __uint_as_float(((unsigned)(unsigned short)s) << 16);
}
struct HL { short h, l; };
__device__ __forceinline__ HL bf16split(float x) {
    HL r;
    r.h = bf16rn(x);
    r.l = bf16rn(x - bf16tof(r.h));
    return r;
}
__device__ __forceinline__ void dma16(const short* g, short* l) {
    __builtin_amdgcn_global_load_lds(
        (const __attribute__((address_space(1))) unsigned int*)g,
        (__attribute__((address_space(3))) unsigned int*)l, 16, 0, 0);
}
// pack (truncate) two f32 -> two bf16 in one dword (lo = f0, hi = f1)
__device__ __forceinline__ unsigned packbf2(float f0, float f1) {
    return __builtin_amdgcn_perm(__float_as_uint(f1), __float_as_uint(f0), 0x07060302);
}

// 16x16x16 bf16 MFMA (A,B: 4 bf16 = 2 VGPR); builtin name varies.
#if defined(__has_builtin)
#if __has_builtin(__builtin_amdgcn_mfma_f32_16x16x16bf16_1k)
#define HAVE_MFMA16_BUILTIN 1
__device__ __forceinline__ f32x4 mfma16(short4v a, short4v b, f32x4 c) {
    return __builtin_amdgcn_mfma_f32_16x16x16bf16_1k(a, b, c, 0, 0, 0);
}
#elif __has_builtin(__builtin_amdgcn_mfma_f32_16x16x16_bf16)
#define HAVE_MFMA16_BUILTIN 1
__device__ __forceinline__ f32x4 mfma16(short4v a, short4v b, f32x4 c) {
    return __builtin_amdgcn_mfma_f32_16x16x16_bf16(a, b, c, 0, 0, 0);
}
#endif
#endif
#ifndef HAVE_MFMA16_BUILTIN
__device__ __forceinline__ f32x4 mfma16(short4v a, short4v b, f32x4 c) {
    asm("s_nop 1\n\tv_mfma_f32_16x16x16_bf16 %0, %1, %2, %0"
        : "+v"(c) : "v"(a), "v"(b));
    return c;
}
#endif

// Fragment-order conventions (verified end-to-end R2/R4-R13, R19):
//  A-frag (16x16x32): lane=(q,r), element A[m=r][k=q*8+j]; B-frag identical.
//  A/B-frag (16x16x16): lane=(q,r), element [r][k=q*4+j], j=0..3.
//  C/D   : D[m=q*4+reg][ncol=r]
// K frag buffer: [b][t16][ic8][lane64][j8]; Q: [b][h][nt64][kc2][lane64][j8]
// V frag buffer (R20, 16x16x16 B-frag order): [b][t16][ic16][lane64][j4]
//   where ic = c4*4 + tv: element V[key=t*64+c4*16+(lane>>4)*4+j][v=tv*16+(lane&15)]
// O frag buffer:    [b][nt64][ct16][lane64][j8]

// ---------------------------------------------------------------------------
// prepack_all (unchanged from R13)
// ---------------------------------------------------------------------------
__global__ __launch_bounds__(256) void prepack_all(const float* __restrict__ x,
                                                   const float* __restrict__ qp,
                                                   const float* __restrict__ kp,
                                                   const float* __restrict__ vp,
                                                   const float* __restrict__ wout,
                                                   short* __restrict__ whi,
                                                   short* __restrict__ wlo,
                                                   short* __restrict__ xhi,
                                                   short* __restrict__ xlo,
                                                   short* __restrict__ wof) {
    __shared__ float Cs[64][65];
    const int blk = blockIdx.x;
    const int t = threadIdx.x;
    if (blk < 1024) {
        const int nt = blk & 15, dt = (blk >> 4) & 7, b = blk >> 7;
        #pragma unroll
        for (int i = 0; i < 4; ++i) {
            int row = (t >> 4) + i * 16;
            float4 v = *(const float4*)(x + ((size_t)(b * DIMD + dt * 64 + row)) * NTOK
                                          + nt * 64 + (t & 15) * 4);
            Cs[row][(t & 15) * 4 + 0] = v.x;
            Cs[row][(t & 15) * 4 + 1] = v.y;
            Cs[row][(t & 15) * 4 + 2] = v.z;
            Cs[row][(t & 15) * 4 + 3] = v.w;
        }
        __syncthreads();
        for (int u = t; u < 512; u += 256) {
            int lane2 = u & 63, cidx = u >> 6;
            int q2 = lane2 >> 4, r2 = lane2 & 15;
            int kt_loc = cidx & 1, mt_loc = cidx >> 1;
            short8 h8, l8;
            #pragma unroll
            for (int j = 0; j < 8; ++j) {
                HL s = bf16split(Cs[kt_loc * 32 + q2 * 8 + j][mt_loc * 16 + r2]);
                h8[j] = s.h; l8[j] = s.l;
            }
            size_t off = (((size_t)(b * 64 + nt * 4 + mt_loc)) * 16 + dt * 2 + kt_loc) * 512
                         + lane2 * 8;
            *(short8*)&xhi[off] = h8;
            *(short8*)&xlo[off] = l8;
        }
    } else if (blk < 1184) {
        int tid = (blk - 1024) * 256 + t;
        int lane = tid & 63, kt = (tid >> 6) & 15, ct = tid >> 10;
        int q = lane >> 4, r = lane & 15;
        int c = ct * 16 + r;
        short8 h, l;
        #pragma unroll
        for (int j = 0; j < 8; ++j) {
            int d = kt * 32 + q * 8 + j;
            float v;
            if (c < 64)       v = kp[d * 64 + c];
            else if (c < 128) v = vp[d * 64 + (c - 64)];
            else              v = qp[(size_t)(c - 128) * DIMD + d];
            HL s = bf16split(v);
            h[j] = s.h; l[j] = s.l;
        }
        *(short8*)&whi[(size_t)tid * 8] = h;
        *(short8*)&wlo[(size_t)tid * 8] = l;
    } else {
        int tid = (blk - 1184) * 256 + t;
        int lane = tid & 63, kt = (tid >> 6) & 15, mt = tid >> 10;
        int q = lane >> 4, r = lane & 15;
        const float* src = wout + (size_t)(mt * 16 + r) * DOUT + kt * 32 + q * 8;
        short8 h;
        #pragma unroll
        for (int j = 0; j < 8; ++j) h[j] = bf16rn(src[j]);
        *(short8*)&wof[(size_t)tid * 8] = h;
    }
}

// ---------------------------------------------------------------------------
// qkv_gemm: unchanged main loop; cb==1 (V) emits 16x16x16 B-frag order
// [ic16][lane64][j4] (R20, proven conflict-free).
// ---------------------------------------------------------------------------
__global__ __launch_bounds__(256) void qkv_gemm(const short* __restrict__ xhi,
                                                const short* __restrict__ xlo,
                                                const short* __restrict__ whi,
                                                const short* __restrict__ wlo,
                                                short* __restrict__ khi,
                                                short* __restrict__ klo,
                                                short* __restrict__ vf,
                                                short* __restrict__ qhi,
                                                short* __restrict__ qlo) {
    __shared__ __align__(16) char pool[49152];
    short* Ah = (short*)pool;            // 8192 shorts (16 KB)
    short* Al = Ah + 8192;               // 16 KB
    short* Bh = Al + 8192;               // 4096 shorts (8 KB)
    short* Bl = Bh + 4096;               // 8 KB
    float (*Cs)[65] = (float(*)[65])pool;   // 128*65*4 = 33280 B (alias)

    // XCD swizzle: idx = (g&7) + 8*((g>>3)*10 + cb), g = M-tile id [0,64)
    const int idx = blockIdx.x;
    const int low = idx & 7, rest = idx >> 3;
    const int cb = rest % 10, gh = rest / 10;
    const int g = gh * 8 + low;
    const int b = g >> 3, bml = g & 7;      // rows n0 = bml*128

    const int tid = threadIdx.x, w = tid >> 6, lane = tid & 63;
    const int q = lane >> 4, r = lane & 15;
    f32x4 acc[2][4];
    #pragma unroll
    for (int i = 0; i < 2; ++i)
        #pragma unroll
        for (int j = 0; j < 4; ++j) acc[i][j] = (f32x4){0.f, 0.f, 0.f, 0.f};

    for (int it = 0; it < 8; ++it) {
        __syncthreads();
        for (int u = w; u < 16; u += 4) {
            size_t ga = ((size_t)((b * 64 + bml * 8 + (u >> 1)) * 16 + it * 2 + (u & 1))) * 512 + lane * 8;
            dma16(xhi + ga, &Ah[u * 512]);
            dma16(xlo + ga, &Al[u * 512]);
            if (u < 8) {
                size_t gb = ((size_t)((cb * 4 + (u >> 1)) * 16 + it * 2 + (u & 1))) * 512 + lane * 8;
                dma16(whi + gb, &Bh[u * 512]);
                dma16(wlo + gb, &Bl[u * 512]);
            }
        }
        __syncthreads();
        #pragma unroll
        for (int kc = 0; kc < 2; ++kc) {
            short8 ah[2], al[2];
            #pragma unroll
            for (int rt = 0; rt < 2; ++rt) {
                ah[rt] = *(short8*)&Ah[((w * 2 + rt) * 2 + kc) * 512 + lane * 8];
                al[rt] = *(short8*)&Al[((w * 2 + rt) * 2 + kc) * 512 + lane * 8];
            }
            #pragma unroll
            for (int tt = 0; tt < 4; ++tt) {
                short8 bh = *(short8*)&Bh[(tt * 2 + kc) * 512 + lane * 8];
                short8 bl = *(short8*)&Bl[(tt * 2 + kc) * 512 + lane * 8];
                #pragma unroll
                for (int rt = 0; rt < 2; ++rt) {
                    acc[rt][tt] = __builtin_amdgcn_mfma_f32_16x16x32_bf16(ah[rt], bh, acc[rt][tt], 0, 0, 0);
                    acc[rt][tt] = __builtin_amdgcn_mfma_f32_16x16x32_bf16(ah[rt], bl, acc[rt][tt], 0, 0, 0);
                    acc[rt][tt] = __builtin_amdgcn_mfma_f32_16x16x32_bf16(al[rt], bh, acc[rt][tt], 0, 0, 0);
                }
            }
        }
    }

    // ---- fused epilogue: C tile (128x64) -> LDS -> frag-order bf16 global ----
    __syncthreads();
    #pragma unroll
    for (int rt = 0; rt < 2; ++rt)
        #pragma unroll
        for (int reg = 0; reg < 4; ++reg)
            #pragma unroll
            for (int tt = 0; tt < 4; ++tt)
                Cs[w * 32 + rt * 16 + q * 4 + reg][tt * 16 + r] = acc[rt][tt][reg];
    __syncthreads();

    if (cb == 0) {
        // K: 2 t-tiles; elem K[m=t*64+i*16+r2][kd=cc*32+q2*8+j], ic=i*2+cc
        for (int u = tid; u < 1024; u += 256) {
            int lane2 = u & 63, ic = (u >> 6) & 7, tl = u >> 9;
            int q2 = lane2 >> 4, r2 = lane2 & 15;
            int i = ic >> 1, cc = ic & 1;
            short8 h8, l8;
            #pragma unroll
            for (int j = 0; j < 8; ++j) {
                HL s = bf16split(Cs[tl * 64 + i * 16 + r2][cc * 32 + q2 * 8 + j]);
                h8[j] = s.h; l8[j] = s.l;
            }
            size_t off = ((size_t)(b * 16 + bml * 2 + tl) * 8 + ic) * 512 + lane2 * 8;
            *(short8*)&khi[off] = h8;
            *(short8*)&klo[off] = l8;
        }
    } else if (cb == 1) {
        // V (R20): 16x16x16 B-frag order.  ic = c4*4+tv; element
        // V[key = tl*64 + c4*16 + qn*4 + j][v = tv*16 + r].
        for (int u = tid; u < 1024; u += 256) {
            int a = u & 31, ic = (u >> 5) & 15, tl = u >> 9;
            int c4 = ic >> 2, tv = ic & 3;
            short8 v8;
            #pragma unroll
            for (int jj = 0; jj < 8; ++jj) {
                int lane2 = a * 2 + (jj >> 2), j = jj & 3;
                int qn = lane2 >> 4, r2 = lane2 & 15;
                v8[jj] = bf16rn(Cs[tl * 64 + c4 * 16 + qn * 4 + j][tv * 16 + r2]);
            }
            size_t off = ((size_t)(b * 16 + bml * 2 + tl) * 16 + ic) * 256 + a * 8;
            *(short8*)&vf[off] = v8;
        }
    } else {
        // Q head hd: 8 nt-tiles x 2 kc = 16 chunks
        const int hd = cb - 2;
        const float qscale = 0.125f * 1.44269504f;
        for (int u = tid; u < 1024; u += 256) {
            int lane2 = u & 63, ch = u >> 6;        // ch in [0,16)
            int q2 = lane2 >> 4, r2 = lane2 & 15;
            int kc = ch & 1, ntl = ch >> 1;         // ntl in [0,8)
            short8 h8, l8;
            #pragma unroll
            for (int j = 0; j < 8; ++j) {
                HL s = bf16split(Cs[ntl * 16 + r2][kc * 32 + q2 * 8 + j] * qscale);
                h8[j] = s.h; l8[j] = s.l;
            }
            size_t off = ((((size_t)(b * 8 + hd) * 64 + bml * 8 + ntl) * 2 + kc) * 64 + lane2) * 8;
            *(short8*)&qhi[off] = h8;
            *(short8*)&qlo[off] = l8;
        }
    }
}

// ---------------------------------------------------------------------------
// attn: R22 (resubmitted R23 — prior round was a broker acquisition timeout;
// kernel never ran).  R20 post-mortem: 2-qtile amortization worked
// (conflicts 0, LDS halved) but halved wave count -> 8 waves/CU,
// latency-exposed (59 µs).  Fix: restore 4096 waves via KV-split.  512 thr /
// 8 waves: wave = (p = q-pair 0..3, kh = KV-half 0..1).  Each wave: 2 q-tiles
// x its 8 KV-tiles.  Staging per-half, double-buffered at 32-key subtile
// granularity (2 halves x 2 bufs x 12 KB = 48 KB -> 2 blocks/CU =
// 16 waves/CU), proven 1-barrier pipelined protocol (pinned vmcnt/lgkm
// drain, R16).  After the loop the two halves merge online-softmax state
// (m, l, O) through the dead staging pool (one extra barrier); kh=0 stores.
// ---------------------------------------------------------------------------
__global__ __launch_bounds__(512) void attn_mfma(const short* __restrict__ qhi_g,
                                                 const short* __restrict__ qlo_g,
                                                 const short* __restrict__ khi_g,
                                                 const short* __restrict__ klo_g,
                                                 const short* __restrict__ vf_g,
                                                 short* __restrict__ ob) {
    __shared__ __align__(16) char pool[49152];   // staging / merge-state alias
    short* S0 = (short*)pool;                    // [kh2][buf2][6144 shorts]
    float* Sm = (float*)pool;                    // merge state [p4][lane64][44]

    const int blk = blockIdx.x;
    const int b   = blk & 7;        // XCD = blk%8 = b -> per-XCD K/V L2 locality
    const int h   = (blk >> 3) & 7;
    const int qt  = blk >> 6;
    const int tid = threadIdx.x;
    const int w    = tid >> 6;      // 8 waves
    const int lane = tid & 63;
    const int q    = lane >> 4;
    const int r    = lane & 15;
    const int p    = w & 3;         // q-pair index
    const int kh   = w >> 2;        // KV half: tiles kh*8 .. kh*8+7

    short8 qhi[2][2], qlo[2][2];    // [rt][c]
    #pragma unroll
    for (int rt = 0; rt < 2; ++rt) {
        const int nt = qt * 8 + p * 2 + rt;
        #pragma unroll
        for (int c = 0; c < 2; ++c) {
            size_t off = ((((size_t)(b * 8 + h) * 64 + nt) * 2 + c) * 64 + lane) * 8;
            qhi[rt][c] = *(const short8*)&qhi_g[off];
            qlo[rt][c] = *(const short8*)&qlo_g[off];
        }
    }

    short4v bones4;
    #pragma unroll
    for (int j = 0; j < 4; ++j) bones4[j] = (short)0x3F80;

    f32x4 oacc[2][4], lacc[2];
    float m_[2];
    #pragma unroll
    for (int rt = 0; rt < 2; ++rt) {
        #pragma unroll
        for (int tt = 0; tt < 4; ++tt) oacc[rt][tt] = (f32x4){0.f, 0.f, 0.f, 0.f};
        lacc[rt] = (f32x4){0.f, 0.f, 0.f, 0.f};
        m_[rt] = -1e30f;
    }

    // stage 32-key subtile u (0..15) of this wave's half into buf:
    // layout within 6144-short buffer: Khi [0,2048), Klo [2048,4096), V [4096,6144)
    // 12 dma chunks per subtile, 3 per wave (4 staging waves per half).
    #define STAGE(u_, buf_) {                                                   \
        int t_ = kh * 8 + ((u_) >> 1), s_ = (u_) & 1;                           \
        short* reg_ = S0 + (kh * 2 + (buf_)) * 6144;                            \
        size_t kb_ = ((size_t)((b * 16 + t_) * 8 + s_ * 4 + p)) * 512 + lane * 8; \
        dma16(khi_g + kb_, reg_ + p * 512);                                     \
        dma16(klo_g + kb_, reg_ + 2048 + p * 512);                              \
        size_t vb_ = ((size_t)((b * 16 + t_) * 16 + s_ * 8 + p * 2)) * 256 + lane * 8; \
        dma16(vf_g + vb_, reg_ + 4096 + p * 512);                               \
    }

    STAGE(0, 0);

    for (int u = 0; u < 16; ++u) {
        const int cur = u & 1;
        // pinned drain (proven R16): own DMA landed (vmcnt) + own ds_reads of
        // buf[cur^1] retired (lgkm) before the barrier (trap #18).
        __builtin_amdgcn_sched_barrier(0);
        asm volatile("s_waitcnt vmcnt(0) lgkmcnt(0)" ::: "memory");
        __builtin_amdgcn_sched_barrier(0);
        __syncthreads();
        if (u < 15) STAGE(u + 1, cur ^ 1);

        const short* reg = S0 + (kh * 2 + cur) * 6144;

        // ---- swapped QK^T over 32 keys: sT[rt][i2] lane(q,r) reg holds
        //      S[key = i2*16 + q*4 + reg][row=r]  (split-bf16 3-term) ----
        f32x4 sT[2][2];
        #pragma unroll
        for (int rt = 0; rt < 2; ++rt)
            #pragma unroll
            for (int i2 = 0; i2 < 2; ++i2) sT[rt][i2] = (f32x4){0.f, 0.f, 0.f, 0.f};
        #pragma unroll
        for (int cc = 0; cc < 2; ++cc) {
            #pragma unroll
            for (int i2 = 0; i2 < 2; ++i2) {
                short8 kh8 = *(short8*)&reg[(i2 * 2 + cc) * 512 + lane * 8];
                short8 kl8 = *(short8*)&reg[2048 + (i2 * 2 + cc) * 512 + lane * 8];
                #pragma unroll
                for (int rt = 0; rt < 2; ++rt) {
                    sT[rt][i2] = __builtin_amdgcn_mfma_f32_16x16x32_bf16(kh8, qhi[rt][cc], sT[rt][i2], 0, 0, 0);
                    sT[rt][i2] = __builtin_amdgcn_mfma_f32_16x16x32_bf16(kl8, qhi[rt][cc], sT[rt][i2], 0, 0, 0);
                    sT[rt][i2] = __builtin_amdgcn_mfma_f32_16x16x32_bf16(kh8, qlo[rt][cc], sT[rt][i2], 0, 0, 0);
                }
            }
        }

        // ---- lazy online softmax (log2 space; m_ per lane = row r) ----
        float pm[2];
        #pragma unroll
        for (int rt = 0; rt < 2; ++rt) {
            float a0 = fmaxf(fmaxf(sT[rt][0][0], sT[rt][0][1]), fmaxf(sT[rt][0][2], sT[rt][0][3]));
            float a1 = fmaxf(fmaxf(sT[rt][1][0], sT[rt][1][1]), fmaxf(sT[rt][1][2], sT[rt][1][3]));
            pm[rt] = fmaxf(a0, a1);
        }
        bool need = (pm[0] > m_[0] + 30.f) || (pm[1] > m_[1] + 30.f);
        if (__any((int)need)) {
            #pragma unroll
            for (int rt = 0; rt < 2; ++rt) {
                float full = fmaxf(pm[rt], __shfl_xor(pm[rt], 16));
                full = fmaxf(full, __shfl_xor(full, 32));
                float nm = fmaxf(m_[rt], full);
                float alpha = exp2f(m_[rt] - nm);
                m_[rt] = nm;
                #pragma unroll
                for (int reg2 = 0; reg2 < 4; ++reg2) {
                    float areg = __shfl(alpha, q * 20 + reg2);
                    lacc[rt][reg2] *= areg;
                    #pragma unroll
                    for (int tt = 0; tt < 4; ++tt) oacc[rt][tt][reg2] *= areg;
                }
            }
        }
        #pragma unroll
        for (int rt = 0; rt < 2; ++rt)
            #pragma unroll
            for (int i2 = 0; i2 < 2; ++i2)
                #pragma unroll
                for (int reg2 = 0; reg2 < 4; ++reg2)
                    sT[rt][i2][reg2] = exp2f(sT[rt][i2][reg2] - m_[rt]);

        // ---- PV: register-P (16x16x16 A-frag), V frag read once/2 q-tiles ----
        #pragma unroll
        for (int c2 = 0; c2 < 2; ++c2) {
            short4v pf[2];
            #pragma unroll
            for (int rt = 0; rt < 2; ++rt) {
                union { uint2 u; short4v s; } pk;
                pk.u.x = packbf2(sT[rt][c2][0], sT[rt][c2][1]);
                pk.u.y = packbf2(sT[rt][c2][2], sT[rt][c2][3]);
                pf[rt] = pk.s;
                lacc[rt] = mfma16(pf[rt], bones4, lacc[rt]);
            }
            #pragma unroll
            for (int tt = 0; tt < 4; ++tt) {
                short4v vfr = *(const short4v*)&reg[4096 + (c2 * 4 + tt) * 256 + lane * 4];
                #pragma unroll
                for (int rt = 0; rt < 2; ++rt)
                    oacc[rt][tt] = mfma16(pf[rt], vfr, oacc[rt][tt]);
            }
        }
    }
    #undef STAGE

    // ---- merge the two KV-half states through the dead staging pool ----
    // drain: no DMA outstanding (last stage consumed), all ds_reads retired.
    __builtin_amdgcn_sched_barrier(0);
    asm volatile("s_waitcnt vmcnt(0) lgkmcnt(0)" ::: "memory");
    __builtin_amdgcn_sched_barrier(0);
    __syncthreads();
    // hazard guard for inline-asm mfma16 fallback (MFMA write -> VALU read)
    asm volatile("s_nop 7\n\ts_nop 7" :::);

    float* st = Sm + ((size_t)(p * 64 + lane)) * 44;   // 44 f32/lane, 16B-aligned
    if (kh == 1) {
        #pragma unroll
        for (int rt = 0; rt < 2; ++rt) {
            #pragma unroll
            for (int tt = 0; tt < 4; ++tt)
                *(f32x4*)&st[rt * 16 + tt * 4] = oacc[rt][tt];
            *(f32x4*)&st[32 + rt * 4] = lacc[rt];
            st[40 + rt] = m_[rt];
        }
    }
    __syncthreads();
    if (kh == 0) {
        #pragma unroll
        for (int rt = 0; rt < 2; ++rt) {
            const int nt = qt * 8 + p * 2 + rt;
            float mB = st[40 + rt];
            float nm = fmaxf(m_[rt], mB);
            float aA = exp2f(m_[rt] - nm);
            float aB = exp2f(mB - nm);
            f32x4 lB = *(f32x4*)&st[32 + rt * 4];
            f32x4 oB[4];
            #pragma unroll
            for (int tt = 0; tt < 4; ++tt) oB[tt] = *(f32x4*)&st[rt * 16 + tt * 4];
            #pragma unroll
            for (int reg2 = 0; reg2 < 4; ++reg2) {
                float aAr = __shfl(aA, q * 20 + reg2);
                float aBr = __shfl(aB, q * 20 + reg2);
                float l = aAr * lacc[rt][reg2] + aBr * lB[reg2];
                float inv = 1.f / l;
                #pragma unroll
                for (int tt = 0; tt < 4; ++tt) {
                    float o = aAr * oacc[rt][tt][reg2] + aBr * oB[tt][reg2];
                    int ct = h * 2 + (tt >> 1);
                    int lanep = ((tt & 1) * 2 + (r >> 3)) * 16 + q * 4 + reg2;
                    ob[((((size_t)b * 64 + nt) * 16 + ct) * 64 + lanep) * 8 + (r & 7)] =
                        bf16rn(o * inv);
                }
            }
        }
    }
}

// ---------------------------------------------------------------------------
// out_gemm: plain bf16 MFMA, double-buffered staging (unchanged).
// ---------------------------------------------------------------------------
__global__ __launch_bounds__(256) void out_gemm(const short* __restrict__ wof,
                                                const short* __restrict__ obf,
                                                float* __restrict__ out) {
    __shared__ short Ah[2][4096];
    __shared__ short Bh[2][4096];
    const int b = blockIdx.z, bd = blockIdx.y, bn = blockIdx.x;
    const int tid = threadIdx.x, w = tid >> 6, lane = tid & 63;
    const int q = lane >> 4, r = lane & 15;
    f32x4 acc[4];
    #pragma unroll
    for (int j = 0; j < 4; ++j) acc[j] = (f32x4){0.f, 0.f, 0.f, 0.f};

    for (int u = w; u < 8; u += 4) {
        size_t ga = ((size_t)((bd * 4 + (u >> 1)) * 16 + (u & 1))) * 512 + lane * 8;
        dma16(wof + ga, &Ah[0][u * 512]);
        size_t gb = ((size_t)((b * 64 + bn * 4 + (u >> 1)) * 16 + (u & 1))) * 512 + lane * 8;
        dma16(obf + gb, &Bh[0][u * 512]);
    }

    for (int it = 0; it < 8; ++it) {
        const int cur = it & 1;
        __syncthreads();
        if (it < 7) {
            for (int u = w; u < 8; u += 4) {
                size_t ga = ((size_t)((bd * 4 + (u >> 1)) * 16 + (it + 1) * 2 + (u & 1))) * 512 + lane * 8;
                dma16(wof + ga, &Ah[cur ^ 1][u * 512]);
                size_t gb = ((size_t)((b * 64 + bn * 4 + (u >> 1)) * 16 + (it + 1) * 2 + (u & 1))) * 512 + lane * 8;
                dma16(obf + gb, &Bh[cur ^ 1][u * 512]);
            }
        }
        #pragma unroll
        for (int kc = 0; kc < 2; ++kc) {
            short8 a = *(short8*)&Ah[cur][(w * 2 + kc) * 512 + lane * 8];
            #pragma unroll
            for (int tt = 0; tt < 4; ++tt) {
                short8 bb = *(short8*)&Bh[cur][(tt * 2 + kc) * 512 + lane * 8];
                acc[tt] = __builtin_amdgcn_mfma_f32_16x16x32_bf16(a, bb, acc[tt], 0, 0, 0);
            }
        }
    }
    const int d_base = bd * 64 + w * 16;
    #pragma unroll
    for (int reg = 0; reg < 4; ++reg)
        #pragma unroll
        for (int tt = 0; tt < 4; ++tt)
            out[((size_t)b * DOUT + d_base + q * 4 + reg) * NTOK
                + bn * 64 + tt * 16 + r] = acc[tt][reg];
}

// ---------------------------------------------------------------------------
extern "C" void kernel_launch(void* const* d_in, const int* in_sizes, int n_in,
                              void* d_out, int out_size, void* d_ws, size_t ws_size,
                              hipStream_t stream) {
    const float* x  = (const float*)d_in[0];
    const float* qp = (const float*)d_in[1];
    const float* kp = (const float*)d_in[2];
    const float* vp = (const float*)d_in[3];
    const float* op = (const float*)d_in[4];
    float* out = (float*)d_out;

    // workspace: 38.5 MB (proven R12/R13)
    short* Whi = (short*)d_ws;                 // 327,680
    short* Wlo = Whi + 327680;                 // 327,680
    short* Xhi = Wlo + 327680;                 // 4,194,304
    short* Xlo = Xhi + 4194304;                // 4,194,304
    short* Qhi = Xlo + 4194304;                // 4,194,304
    short* Qlo = Qhi + 4194304;                // 4,194,304
    short* Khi = Qlo + 4194304;                // 524,288
    short* Klo = Khi + 524288;                 // 524,288
    short* Vf  = Klo + 524288;                 // 524,288
    short* Wof = Vf  + 524288;                 // 262,144
    short* Ob  = Xhi;                          // alias: X dead after qkv_gemm

    prepack_all <<<1312, 256, 0, stream>>>(x, qp, kp, vp, op,
                                           Whi, Wlo, Xhi, Xlo, Wof);
    qkv_gemm    <<<640, 256, 0, stream>>>(Xhi, Xlo, Whi, Wlo,
                                          Khi, Klo, Vf, Qhi, Qlo);
    attn_mfma   <<<512, 512, 0, stream>>>(Qhi, Qlo, Khi, Klo, Vf, Ob);
    out_gemm    <<<dim3(16, 8, BATCH), 256, 0, stream>>>(Wof, Ob, out);
}

// Round 11
// 153.281 us; speedup vs baseline: 1.0815x; 1.0815x over previous
//
#include <hip/hip_runtime.h>
#include <math.h>

#define BATCH 8
#define DIMD  512
#define NTOK  1024
#define NH    8
#define CQKV  640
#define DOUT  512

typedef __attribute__((ext_vector_type(8))) short short8;
typedef __attribute__((ext_vector_type(4))) short short4v;
typedef __attribute__((ext_vector_type(4))) float f32x4;

__device__ __forceinline__ short bf16rn(float x) {
    unsigned u = __float_as_uint(x);
    u += 0x7FFF + ((u >> 16) & 1);
    return (short)(u >> 16);
}
__device__ __forceinline__ float bf16tof(short s) {
    return __uint_as_float(((unsigned)(unsigned short)s) << 16);
}
struct HL { short h, l; };
__device__ __forceinline__ HL bf16split(float x) {
    HL r;
    r.h = bf16rn(x);
    r.l = bf16rn(x - bf16tof(r.h));
    return r;
}
__device__ __forceinline__ void dma16(const short* g, short* l) {
    __builtin_amdgcn_global_load_lds(
        (const __attribute__((address_space(1))) unsigned int*)g,
        (__attribute__((address_space(3))) unsigned int*)l, 16, 0, 0);
}
// pack (truncate) two f32 -> two bf16 in one dword (lo = f0, hi = f1)
__device__ __forceinline__ unsigned packbf2(float f0, float f1) {
    return __builtin_amdgcn_perm(__float_as_uint(f1), __float_as_uint(f0), 0x07060302);
}

// 16x16x16 bf16 MFMA (A,B: 4 bf16 = 2 VGPR); builtin name varies.
#if defined(__has_builtin)
#if __has_builtin(__builtin_amdgcn_mfma_f32_16x16x16bf16_1k)
#define HAVE_MFMA16_BUILTIN 1
__device__ __forceinline__ f32x4 mfma16(short4v a, short4v b, f32x4 c) {
    return __builtin_amdgcn_mfma_f32_16x16x16bf16_1k(a, b, c, 0, 0, 0);
}
#elif __has_builtin(__builtin_amdgcn_mfma_f32_16x16x16_bf16)
#define HAVE_MFMA16_BUILTIN 1
__device__ __forceinline__ f32x4 mfma16(short4v a, short4v b, f32x4 c) {
    return __builtin_amdgcn_mfma_f32_16x16x16_bf16(a, b, c, 0, 0, 0);
}
#endif
#endif
#ifndef HAVE_MFMA16_BUILTIN
__device__ __forceinline__ f32x4 mfma16(short4v a, short4v b, f32x4 c) {
    asm("s_nop 1\n\tv_mfma_f32_16x16x16_bf16 %0, %1, %2, %0"
        : "+v"(c) : "v"(a), "v"(b));
    return c;
}
#endif

// Fragment-order conventions (verified end-to-end R2/R4-R13, R19, R20):
//  A-frag (16x16x32): lane=(q,r), element A[m=r][k=q*8+j]; B-frag identical.
//  A/B-frag (16x16x16): lane=(q,r), element [r][k=q*4+j], j=0..3.
//  C/D   : D[m=q*4+reg][ncol=r]
// K frag buffer: [b][t16][ic8][lane64][j8]; Q: [b][h][nt64][kc2][lane64][j8]
// V frag buffer (R20, 16x16x16 B-frag order): [b][t16][ic16][lane64][j4]
//   where ic = c4*4 + tv: element V[key=t*64+c4*16+(lane>>4)*4+j][v=tv*16+(lane&15)]
// O frag buffer:    [b][nt64][ct16][lane64][j8]

// ---------------------------------------------------------------------------
// prepack_all (unchanged from R13)
// ---------------------------------------------------------------------------
__global__ __launch_bounds__(256) void prepack_all(const float* __restrict__ x,
                                                   const float* __restrict__ qp,
                                                   const float* __restrict__ kp,
                                                   const float* __restrict__ vp,
                                                   const float* __restrict__ wout,
                                                   short* __restrict__ whi,
                                                   short* __restrict__ wlo,
                                                   short* __restrict__ xhi,
                                                   short* __restrict__ xlo,
                                                   short* __restrict__ wof) {
    __shared__ float Cs[64][65];
    const int blk = blockIdx.x;
    const int t = threadIdx.x;
    if (blk < 1024) {
        const int nt = blk & 15, dt = (blk >> 4) & 7, b = blk >> 7;
        #pragma unroll
        for (int i = 0; i < 4; ++i) {
            int row = (t >> 4) + i * 16;
            float4 v = *(const float4*)(x + ((size_t)(b * DIMD + dt * 64 + row)) * NTOK
                                          + nt * 64 + (t & 15) * 4);
            Cs[row][(t & 15) * 4 + 0] = v.x;
            Cs[row][(t & 15) * 4 + 1] = v.y;
            Cs[row][(t & 15) * 4 + 2] = v.z;
            Cs[row][(t & 15) * 4 + 3] = v.w;
        }
        __syncthreads();
        for (int u = t; u < 512; u += 256) {
            int lane2 = u & 63, cidx = u >> 6;
            int q2 = lane2 >> 4, r2 = lane2 & 15;
            int kt_loc = cidx & 1, mt_loc = cidx >> 1;
            short8 h8, l8;
            #pragma unroll
            for (int j = 0; j < 8; ++j) {
                HL s = bf16split(Cs[kt_loc * 32 + q2 * 8 + j][mt_loc * 16 + r2]);
                h8[j] = s.h; l8[j] = s.l;
            }
            size_t off = (((size_t)(b * 64 + nt * 4 + mt_loc)) * 16 + dt * 2 + kt_loc) * 512
                         + lane2 * 8;
            *(short8*)&xhi[off] = h8;
            *(short8*)&xlo[off] = l8;
        }
    } else if (blk < 1184) {
        int tid = (blk - 1024) * 256 + t;
        int lane = tid & 63, kt = (tid >> 6) & 15, ct = tid >> 10;
        int q = lane >> 4, r = lane & 15;
        int c = ct * 16 + r;
        short8 h, l;
        #pragma unroll
        for (int j = 0; j < 8; ++j) {
            int d = kt * 32 + q * 8 + j;
            float v;
            if (c < 64)       v = kp[d * 64 + c];
            else if (c < 128) v = vp[d * 64 + (c - 64)];
            else              v = qp[(size_t)(c - 128) * DIMD + d];
            HL s = bf16split(v);
            h[j] = s.h; l[j] = s.l;
        }
        *(short8*)&whi[(size_t)tid * 8] = h;
        *(short8*)&wlo[(size_t)tid * 8] = l;
    } else {
        int tid = (blk - 1184) * 256 + t;
        int lane = tid & 63, kt = (tid >> 6) & 15, mt = tid >> 10;
        int q = lane >> 4, r = lane & 15;
        const float* src = wout + (size_t)(mt * 16 + r) * DOUT + kt * 32 + q * 8;
        short8 h;
        #pragma unroll
        for (int j = 0; j < 8; ++j) h[j] = bf16rn(src[j]);
        *(short8*)&wof[(size_t)tid * 8] = h;
    }
}

// ---------------------------------------------------------------------------
// qkv_gemm: unchanged main loop; cb==1 (V) emits 16x16x16 B-frag order
// [ic16][lane64][j4] (R20/R22, proven conflict-free and correct).
// ---------------------------------------------------------------------------
__global__ __launch_bounds__(256) void qkv_gemm(const short* __restrict__ xhi,
                                                const short* __restrict__ xlo,
                                                const short* __restrict__ whi,
                                                const short* __restrict__ wlo,
                                                short* __restrict__ khi,
                                                short* __restrict__ klo,
                                                short* __restrict__ vf,
                                                short* __restrict__ qhi,
                                                short* __restrict__ qlo) {
    __shared__ __align__(16) char pool[49152];
    short* Ah = (short*)pool;            // 8192 shorts (16 KB)
    short* Al = Ah + 8192;               // 16 KB
    short* Bh = Al + 8192;               // 4096 shorts (8 KB)
    short* Bl = Bh + 4096;               // 8 KB
    float (*Cs)[65] = (float(*)[65])pool;   // 128*65*4 = 33280 B (alias)

    // XCD swizzle: idx = (g&7) + 8*((g>>3)*10 + cb), g = M-tile id [0,64)
    const int idx = blockIdx.x;
    const int low = idx & 7, rest = idx >> 3;
    const int cb = rest % 10, gh = rest / 10;
    const int g = gh * 8 + low;
    const int b = g >> 3, bml = g & 7;      // rows n0 = bml*128

    const int tid = threadIdx.x, w = tid >> 6, lane = tid & 63;
    const int q = lane >> 4, r = lane & 15;
    f32x4 acc[2][4];
    #pragma unroll
    for (int i = 0; i < 2; ++i)
        #pragma unroll
        for (int j = 0; j < 4; ++j) acc[i][j] = (f32x4){0.f, 0.f, 0.f, 0.f};

    for (int it = 0; it < 8; ++it) {
        __syncthreads();
        for (int u = w; u < 16; u += 4) {
            size_t ga = ((size_t)((b * 64 + bml * 8 + (u >> 1)) * 16 + it * 2 + (u & 1))) * 512 + lane * 8;
            dma16(xhi + ga, &Ah[u * 512]);
            dma16(xlo + ga, &Al[u * 512]);
            if (u < 8) {
                size_t gb = ((size_t)((cb * 4 + (u >> 1)) * 16 + it * 2 + (u & 1))) * 512 + lane * 8;
                dma16(whi + gb, &Bh[u * 512]);
                dma16(wlo + gb, &Bl[u * 512]);
            }
        }
        __syncthreads();
        #pragma unroll
        for (int kc = 0; kc < 2; ++kc) {
            short8 ah[2], al[2];
            #pragma unroll
            for (int rt = 0; rt < 2; ++rt) {
                ah[rt] = *(short8*)&Ah[((w * 2 + rt) * 2 + kc) * 512 + lane * 8];
                al[rt] = *(short8*)&Al[((w * 2 + rt) * 2 + kc) * 512 + lane * 8];
            }
            #pragma unroll
            for (int tt = 0; tt < 4; ++tt) {
                short8 bh = *(short8*)&Bh[(tt * 2 + kc) * 512 + lane * 8];
                short8 bl = *(short8*)&Bl[(tt * 2 + kc) * 512 + lane * 8];
                #pragma unroll
                for (int rt = 0; rt < 2; ++rt) {
                    acc[rt][tt] = __builtin_amdgcn_mfma_f32_16x16x32_bf16(ah[rt], bh, acc[rt][tt], 0, 0, 0);
                    acc[rt][tt] = __builtin_amdgcn_mfma_f32_16x16x32_bf16(ah[rt], bl, acc[rt][tt], 0, 0, 0);
                    acc[rt][tt] = __builtin_amdgcn_mfma_f32_16x16x32_bf16(al[rt], bh, acc[rt][tt], 0, 0, 0);
                }
            }
        }
    }

    // ---- fused epilogue: C tile (128x64) -> LDS -> frag-order bf16 global ----
    __syncthreads();
    #pragma unroll
    for (int rt = 0; rt < 2; ++rt)
        #pragma unroll
        for (int reg = 0; reg < 4; ++reg)
            #pragma unroll
            for (int tt = 0; tt < 4; ++tt)
                Cs[w * 32 + rt * 16 + q * 4 + reg][tt * 16 + r] = acc[rt][tt][reg];
    __syncthreads();

    if (cb == 0) {
        // K: 2 t-tiles; elem K[m=t*64+i*16+r2][kd=cc*32+q2*8+j], ic=i*2+cc
        for (int u = tid; u < 1024; u += 256) {
            int lane2 = u & 63, ic = (u >> 6) & 7, tl = u >> 9;
            int q2 = lane2 >> 4, r2 = lane2 & 15;
            int i = ic >> 1, cc = ic & 1;
            short8 h8, l8;
            #pragma unroll
            for (int j = 0; j < 8; ++j) {
                HL s = bf16split(Cs[tl * 64 + i * 16 + r2][cc * 32 + q2 * 8 + j]);
                h8[j] = s.h; l8[j] = s.l;
            }
            size_t off = ((size_t)(b * 16 + bml * 2 + tl) * 8 + ic) * 512 + lane2 * 8;
            *(short8*)&khi[off] = h8;
            *(short8*)&klo[off] = l8;
        }
    } else if (cb == 1) {
        // V (R20): 16x16x16 B-frag order.  ic = c4*4+tv; element
        // V[key = tl*64 + c4*16 + qn*4 + j][v = tv*16 + r].
        for (int u = tid; u < 1024; u += 256) {
            int a = u & 31, ic = (u >> 5) & 15, tl = u >> 9;
            int c4 = ic >> 2, tv = ic & 3;
            short8 v8;
            #pragma unroll
            for (int jj = 0; jj < 8; ++jj) {
                int lane2 = a * 2 + (jj >> 2), j = jj & 3;
                int qn = lane2 >> 4, r2 = lane2 & 15;
                v8[jj] = bf16rn(Cs[tl * 64 + c4 * 16 + qn * 4 + j][tv * 16 + r2]);
            }
            size_t off = ((size_t)(b * 16 + bml * 2 + tl) * 16 + ic) * 256 + a * 8;
            *(short8*)&vf[off] = v8;
        }
    } else {
        // Q head hd: 8 nt-tiles x 2 kc = 16 chunks
        const int hd = cb - 2;
        const float qscale = 0.125f * 1.44269504f;
        for (int u = tid; u < 1024; u += 256) {
            int lane2 = u & 63, ch = u >> 6;        // ch in [0,16)
            int q2 = lane2 >> 4, r2 = lane2 & 15;
            int kc = ch & 1, ntl = ch >> 1;         // ntl in [0,8)
            short8 h8, l8;
            #pragma unroll
            for (int j = 0; j < 8; ++j) {
                HL s = bf16split(Cs[ntl * 16 + r2][kc * 32 + q2 * 8 + j] * qscale);
                h8[j] = s.h; l8[j] = s.l;
            }
            size_t off = ((((size_t)(b * 8 + hd) * 64 + bml * 8 + ntl) * 2 + kc) * 64 + lane2) * 8;
            *(short8*)&qhi[off] = h8;
            *(short8*)&qlo[off] = l8;
        }
    }
}

// ---------------------------------------------------------------------------
// attn: R24 (resubmitted R25 — prior round was a broker acquisition timeout;
// kernel never ran).  R24 = R19 structure (proven 55.4 µs: 8 waves x
// 1 q-tile, 64-key tiles, register-P swapped QK^T, 1 barrier/tile
// pinned-drain dbuf staging) + R20's conflict-free V B-frag layout (proven:
// 4.19M conflict cycles -> 0).  R22 post-mortem: KV-split doubled barrier
// frequency per unit compute -> occupancy 20%, 67.5 µs.  Structural trades
// keep losing; this round only combines the two independently-verified wins.
// Per-wave-tile LDS: 16 b128 (K) + 16 conflict-free b64 (V) = ~288 cyc vs
// R19's ~352.
// ---------------------------------------------------------------------------
__global__ __launch_bounds__(512) void attn_mfma(const short* __restrict__ qhi_g,
                                                 const short* __restrict__ qlo_g,
                                                 const short* __restrict__ khi_g,
                                                 const short* __restrict__ klo_g,
                                                 const short* __restrict__ vf_g,
                                                 short* __restrict__ ob) {
    __shared__ short Khi[2][4096], Klo[2][4096], Vf[2][4096];   // 48 KB
    const int blk = blockIdx.x;
    const int b   = blk & 7;        // XCD = blk%8 = b -> per-XCD K/V L2 locality
    const int h   = (blk >> 3) & 7;
    const int qt  = blk >> 6;
    const int tid = threadIdx.x;
    const int w    = tid >> 6;      // 8 waves
    const int lane = tid & 63;
    const int q    = lane >> 4;
    const int r    = lane & 15;
    const int nt = qt * 8 + w;      // this wave's 16-row q-tile

    short8 qhi[2], qlo[2];
    #pragma unroll
    for (int c = 0; c < 2; ++c) {
        size_t off = ((((size_t)(b * 8 + h) * 64 + nt) * 2 + c) * 64 + lane) * 8;
        qhi[c] = *(const short8*)&qhi_g[off];
        qlo[c] = *(const short8*)&qlo_g[off];
    }

    short4v bones4;
    #pragma unroll
    for (int j = 0; j < 4; ++j) bones4[j] = (short)0x3F80;

    f32x4 oacc[4], lacc;
    #pragma unroll
    for (int tt = 0; tt < 4; ++tt) oacc[tt] = (f32x4){0.f, 0.f, 0.f, 0.f};
    lacc = (f32x4){0.f, 0.f, 0.f, 0.f};
    float m_ = -1e30f;              // running row-max (row = r), log2 space

    const int kbase = lane * 8;     // K frag base (shorts)
    const int vbase = lane * 4;     // V frag base (shorts) — lane-contiguous

    // prologue: DMA tile 0 into buffer 0 (each wave stages chunk ch = w)
    {
        const size_t kb = ((size_t)(b * 16 + 0) * 8) * 512;
        dma16(khi_g + kb + w * 512 + lane * 8, &Khi[0][w * 512]);
        dma16(klo_g + kb + w * 512 + lane * 8, &Klo[0][w * 512]);
        dma16(vf_g  + kb + w * 512 + lane * 8, &Vf [0][w * 512]);
    }

    for (int t = 0; t < 16; ++t) {
        const int cur = t & 1;
        // pinned drain: own DMA landed (vmcnt) AND own ds_reads retired (lgkm)
        // before the barrier; closes the trap-#18 race (proven R16-R19).
        __builtin_amdgcn_sched_barrier(0);
        asm volatile("s_waitcnt vmcnt(0) lgkmcnt(0)" ::: "memory");
        __builtin_amdgcn_sched_barrier(0);
        __syncthreads();
        if (t < 15) {               // issue next tile into buf[cur^1]
            const size_t kb = ((size_t)(b * 16 + t + 1) * 8) * 512;
            dma16(khi_g + kb + w * 512 + lane * 8, &Khi[cur ^ 1][w * 512]);
            dma16(klo_g + kb + w * 512 + lane * 8, &Klo[cur ^ 1][w * 512]);
            dma16(vf_g  + kb + w * 512 + lane * 8, &Vf [cur ^ 1][w * 512]);
        }

        // ---- swapped QK^T: sT[i] lane(q,r) reg: S[key=i*16+q*4+reg][row=r]
        //      (split-bf16 3-term) ----
        f32x4 sT[4];
        #pragma unroll
        for (int i = 0; i < 4; ++i) sT[i] = (f32x4){0.f, 0.f, 0.f, 0.f};
        #pragma unroll
        for (int cc = 0; cc < 2; ++cc) {
            #pragma unroll
            for (int i = 0; i < 4; ++i) {
                short8 kh = *(short8*)&Khi[cur][(i * 2 + cc) * 512 + kbase];
                short8 kl = *(short8*)&Klo[cur][(i * 2 + cc) * 512 + kbase];
                sT[i] = __builtin_amdgcn_mfma_f32_16x16x32_bf16(kh, qhi[cc], sT[i], 0, 0, 0);
                sT[i] = __builtin_amdgcn_mfma_f32_16x16x32_bf16(kl, qhi[cc], sT[i], 0, 0, 0);
                sT[i] = __builtin_amdgcn_mfma_f32_16x16x32_bf16(kh, qlo[cc], sT[i], 0, 0, 0);
            }
        }

        // ---- lazy online softmax (log2 space; m_ scalar per lane = row r) ----
        float pm;
        {
            float a0 = fmaxf(fmaxf(sT[0][0], sT[0][1]), fmaxf(sT[0][2], sT[0][3]));
            float a1 = fmaxf(fmaxf(sT[1][0], sT[1][1]), fmaxf(sT[1][2], sT[1][3]));
            float a2 = fmaxf(fmaxf(sT[2][0], sT[2][1]), fmaxf(sT[2][2], sT[2][3]));
            float a3 = fmaxf(fmaxf(sT[3][0], sT[3][1]), fmaxf(sT[3][2], sT[3][3]));
            pm = fmaxf(fmaxf(a0, a1), fmaxf(a2, a3));
        }
        bool need = (pm > m_ + 30.f);
        if (__any((int)need)) {
            // full row max across the 4 q-lanes of row r
            float full = fmaxf(pm, __shfl_xor(pm, 16));
            full = fmaxf(full, __shfl_xor(full, 32));
            float nm = fmaxf(m_, full);
            float alpha = exp2f(m_ - nm);
            m_ = nm;
            // redistribute alpha to oacc/lacc rows (row q*4+reg lives at
            // lane with r' = q*4+reg; pick source lane q*16 + q*4 + reg)
            #pragma unroll
            for (int reg = 0; reg < 4; ++reg) {
                float areg = __shfl(alpha, q * 20 + reg);
                lacc[reg] *= areg;
                #pragma unroll
                for (int tt = 0; tt < 4; ++tt) oacc[tt][reg] *= areg;
            }
        }
        #pragma unroll
        for (int i = 0; i < 4; ++i)
            #pragma unroll
            for (int reg = 0; reg < 4; ++reg)
                sT[i][reg] = exp2f(sT[i][reg] - m_);

        // ---- PV: zero-shuffle register P (16x16x16 A-frag); V frags
        //      lane-contiguous b64 (conflict-free) ----
        #pragma unroll
        for (int c = 0; c < 4; ++c) {
            union { uint2 u; short4v s; } pk;
            pk.u.x = packbf2(sT[c][0], sT[c][1]);
            pk.u.y = packbf2(sT[c][2], sT[c][3]);
            short4v pf = pk.s;
            lacc = mfma16(pf, bones4, lacc);
            #pragma unroll
            for (int tt = 0; tt < 4; ++tt) {
                short4v vfr = *(const short4v*)&Vf[cur][(c * 4 + tt) * 256 + vbase];
                oacc[tt] = mfma16(pf, vfr, oacc[tt]);
            }
        }
    }

    // hazard guard for the inline-asm MFMA fallback (MFMA write -> VALU read)
    asm volatile("s_nop 7\n\ts_nop 7" :::);

    // ---- epilogue: O frag-order bf16 store (D layout unchanged) ----
    #pragma unroll
    for (int reg = 0; reg < 4; ++reg) {
        float inv = 1.f / lacc[reg];
        #pragma unroll
        for (int tt = 0; tt < 4; ++tt) {
            int ct = h * 2 + (tt >> 1);
            int lanep = ((tt & 1) * 2 + (r >> 3)) * 16 + q * 4 + reg;
            ob[((((size_t)b * 64 + nt) * 16 + ct) * 64 + lanep) * 8 + (r & 7)] =
                bf16rn(oacc[tt][reg] * inv);
        }
    }
}

// ---------------------------------------------------------------------------
// out_gemm: plain bf16 MFMA, double-buffered staging (unchanged).
// ---------------------------------------------------------------------------
__global__ __launch_bounds__(256) void out_gemm(const short* __restrict__ wof,
                                                const short* __restrict__ obf,
                                                float* __restrict__ out) {
    __shared__ short Ah[2][4096];
    __shared__ short Bh[2][4096];
    const int b = blockIdx.z, bd = blockIdx.y, bn = blockIdx.x;
    const int tid = threadIdx.x, w = tid >> 6, lane = tid & 63;
    const int q = lane >> 4, r = lane & 15;
    f32x4 acc[4];
    #pragma unroll
    for (int j = 0; j < 4; ++j) acc[j] = (f32x4){0.f, 0.f, 0.f, 0.f};

    for (int u = w; u < 8; u += 4) {
        size_t ga = ((size_t)((bd * 4 + (u >> 1)) * 16 + (u & 1))) * 512 + lane * 8;
        dma16(wof + ga, &Ah[0][u * 512]);
        size_t gb = ((size_t)((b * 64 + bn * 4 + (u >> 1)) * 16 + (u & 1))) * 512 + lane * 8;
        dma16(obf + gb, &Bh[0][u * 512]);
    }

    for (int it = 0; it < 8; ++it) {
        const int cur = it & 1;
        __syncthreads();
        if (it < 7) {
            for (int u = w; u < 8; u += 4) {
                size_t ga = ((size_t)((bd * 4 + (u >> 1)) * 16 + (it + 1) * 2 + (u & 1))) * 512 + lane * 8;
                dma16(wof + ga, &Ah[cur ^ 1][u * 512]);
                size_t gb = ((size_t)((b * 64 + bn * 4 + (u >> 1)) * 16 + (it + 1) * 2 + (u & 1))) * 512 + lane * 8;
                dma16(obf + gb, &Bh[cur ^ 1][u * 512]);
            }
        }
        #pragma unroll
        for (int kc = 0; kc < 2; ++kc) {
            short8 a = *(short8*)&Ah[cur][(w * 2 + kc) * 512 + lane * 8];
            #pragma unroll
            for (int tt = 0; tt < 4; ++tt) {
                short8 bb = *(short8*)&Bh[cur][(tt * 2 + kc) * 512 + lane * 8];
                acc[tt] = __builtin_amdgcn_mfma_f32_16x16x32_bf16(a, bb, acc[tt], 0, 0, 0);
            }
        }
    }
    const int d_base = bd * 64 + w * 16;
    #pragma unroll
    for (int reg = 0; reg < 4; ++reg)
        #pragma unroll
        for (int tt = 0; tt < 4; ++tt)
            out[((size_t)b * DOUT + d_base + q * 4 + reg) * NTOK
                + bn * 64 + tt * 16 + r] = acc[tt][reg];
}

// ---------------------------------------------------------------------------
extern "C" void kernel_launch(void* const* d_in, const int* in_sizes, int n_in,
                              void* d_out, int out_size, void* d_ws, size_t ws_size,
                              hipStream_t stream) {
    const float* x  = (const float*)d_in[0];
    const float* qp = (const float*)d_in[1];
    const float* kp = (const float*)d_in[2];
    const float* vp = (const float*)d_in[3];
    const float* op = (const float*)d_in[4];
    float* out = (float*)d_out;

    // workspace: 38.5 MB (proven R12/R13)
    short* Whi = (short*)d_ws;                 // 327,680
    short* Wlo = Whi + 327680;                 // 327,680
    short* Xhi = Wlo + 327680;                 // 4,194,304
    short* Xlo = Xhi + 4194304;                // 4,194,304
    short* Qhi = Xlo + 4194304;                // 4,194,304
    short* Qlo = Qhi + 4194304;                // 4,194,304
    short* Khi = Qlo + 4194304;                // 524,288
    short* Klo = Khi + 524288;                 // 524,288
    short* Vf  = Klo + 524288;                 // 524,288
    short* Wof = Vf  + 524288;                 // 262,144
    short* Ob  = Xhi;                          // alias: X dead after qkv_gemm

    prepack_all <<<1312, 256, 0, stream>>>(x, qp, kp, vp, op,
                                           Whi, Wlo, Xhi, Xlo, Wof);
    qkv_gemm    <<<640, 256, 0, stream>>>(Xhi, Xlo, Whi, Wlo,
                                          Khi, Klo, Vf, Qhi, Qlo);
    attn_mfma   <<<512, 512, 0, stream>>>(Qhi, Qlo, Khi, Klo, Vf, Ob);
    out_gemm    <<<dim3(16, 8, BATCH), 256, 0, stream>>>(Wof, Ob, out);
}

// Round 12
// 152.326 us; speedup vs baseline: 1.0883x; 1.0063x over previous
//
#include <hip/hip_runtime.h>
#include <math.h>

#define BATCH 8
#define DIMD  512
#define NTOK  1024
#define NH    8
#define CQKV  640
#define DOUT  512

typedef __attribute__((ext_vector_type(8))) short short8;
typedef __attribute__((ext_vector_type(4))) short short4v;
typedef __attribute__((ext_vector_type(4))) float f32x4;

__device__ __forceinline__ short bf16rn(float x) {
    unsigned u = __float_as_uint(x);
    u += 0x7FFF + ((u >> 16) & 1);
    return (short)(u >> 16);
}
__device__ __forceinline__ float bf16tof(short s) {
    return __uint_as_float(((unsigned)(unsigned short)s) << 16);
}
struct HL { short h, l; };
__device__ __forceinline__ HL bf16split(float x) {
    HL r;
    r.h = bf16rn(x);
    r.l = bf16rn(x - bf16tof(r.h));
    return r;
}
__device__ __forceinline__ void dma16(const short* g, short* l) {
    __builtin_amdgcn_global_load_lds(
        (const __attribute__((address_space(1))) unsigned int*)g,
        (__attribute__((address_space(3))) unsigned int*)l, 16, 0, 0);
}
// pack (truncate) two f32 -> two bf16 in one dword (lo = f0, hi = f1)
__device__ __forceinline__ unsigned packbf2(float f0, float f1) {
    return __builtin_amdgcn_perm(__float_as_uint(f1), __float_as_uint(f0), 0x07060302);
}

// 16x16x16 bf16 MFMA (A,B: 4 bf16 = 2 VGPR); builtin name varies.
#if defined(__has_builtin)
#if __has_builtin(__builtin_amdgcn_mfma_f32_16x16x16bf16_1k)
#define HAVE_MFMA16_BUILTIN 1
__device__ __forceinline__ f32x4 mfma16(short4v a, short4v b, f32x4 c) {
    return __builtin_amdgcn_mfma_f32_16x16x16bf16_1k(a, b, c, 0, 0, 0);
}
#elif __has_builtin(__builtin_amdgcn_mfma_f32_16x16x16_bf16)
#define HAVE_MFMA16_BUILTIN 1
__device__ __forceinline__ f32x4 mfma16(short4v a, short4v b, f32x4 c) {
    return __builtin_amdgcn_mfma_f32_16x16x16_bf16(a, b, c, 0, 0, 0);
}
#endif
#endif
#ifndef HAVE_MFMA16_BUILTIN
__device__ __forceinline__ f32x4 mfma16(short4v a, short4v b, f32x4 c) {
    asm("s_nop 1\n\tv_mfma_f32_16x16x16_bf16 %0, %1, %2, %0"
        : "+v"(c) : "v"(a), "v"(b));
    return c;
}
#endif

// Fragment-order conventions (verified end-to-end R2/R4-R13, R19, R20, R24):
//  A-frag (16x16x32): lane=(q,r), element A[m=r][k=q*8+j]; B-frag identical.
//  A/B-frag (16x16x16): lane=(q,r), element [r][k=q*4+j], j=0..3.
//  C/D   : D[m=q*4+reg][ncol=r]
// K frag buffer: [b][t16][ic8][lane64][j8]; Q: [b][h][nt64][kc2][lane64][j8]
// V frag buffer (R20, 16x16x16 B-frag order): [b][t16][ic16][lane64][j4]
//   where ic = c4*4 + tv: element V[key=t*64+c4*16+(lane>>4)*4+j][v=tv*16+(lane&15)]
// O frag buffer:    [b][nt64][ct16][lane64][j8]

// ---------------------------------------------------------------------------
// prepack_all (unchanged from R13)
// ---------------------------------------------------------------------------
__global__ __launch_bounds__(256) void prepack_all(const float* __restrict__ x,
                                                   const float* __restrict__ qp,
                                                   const float* __restrict__ kp,
                                                   const float* __restrict__ vp,
                                                   const float* __restrict__ wout,
                                                   short* __restrict__ whi,
                                                   short* __restrict__ wlo,
                                                   short* __restrict__ xhi,
                                                   short* __restrict__ xlo,
                                                   short* __restrict__ wof) {
    __shared__ float Cs[64][65];
    const int blk = blockIdx.x;
    const int t = threadIdx.x;
    if (blk < 1024) {
        const int nt = blk & 15, dt = (blk >> 4) & 7, b = blk >> 7;
        #pragma unroll
        for (int i = 0; i < 4; ++i) {
            int row = (t >> 4) + i * 16;
            float4 v = *(const float4*)(x + ((size_t)(b * DIMD + dt * 64 + row)) * NTOK
                                          + nt * 64 + (t & 15) * 4);
            Cs[row][(t & 15) * 4 + 0] = v.x;
            Cs[row][(t & 15) * 4 + 1] = v.y;
            Cs[row][(t & 15) * 4 + 2] = v.z;
            Cs[row][(t & 15) * 4 + 3] = v.w;
        }
        __syncthreads();
        for (int u = t; u < 512; u += 256) {
            int lane2 = u & 63, cidx = u >> 6;
            int q2 = lane2 >> 4, r2 = lane2 & 15;
            int kt_loc = cidx & 1, mt_loc = cidx >> 1;
            short8 h8, l8;
            #pragma unroll
            for (int j = 0; j < 8; ++j) {
                HL s = bf16split(Cs[kt_loc * 32 + q2 * 8 + j][mt_loc * 16 + r2]);
                h8[j] = s.h; l8[j] = s.l;
            }
            size_t off = (((size_t)(b * 64 + nt * 4 + mt_loc)) * 16 + dt * 2 + kt_loc) * 512
                         + lane2 * 8;
            *(short8*)&xhi[off] = h8;
            *(short8*)&xlo[off] = l8;
        }
    } else if (blk < 1184) {
        int tid = (blk - 1024) * 256 + t;
        int lane = tid & 63, kt = (tid >> 6) & 15, ct = tid >> 10;
        int q = lane >> 4, r = lane & 15;
        int c = ct * 16 + r;
        short8 h, l;
        #pragma unroll
        for (int j = 0; j < 8; ++j) {
            int d = kt * 32 + q * 8 + j;
            float v;
            if (c < 64)       v = kp[d * 64 + c];
            else if (c < 128) v = vp[d * 64 + (c - 64)];
            else              v = qp[(size_t)(c - 128) * DIMD + d];
            HL s = bf16split(v);
            h[j] = s.h; l[j] = s.l;
        }
        *(short8*)&whi[(size_t)tid * 8] = h;
        *(short8*)&wlo[(size_t)tid * 8] = l;
    } else {
        int tid = (blk - 1184) * 256 + t;
        int lane = tid & 63, kt = (tid >> 6) & 15, mt = tid >> 10;
        int q = lane >> 4, r = lane & 15;
        const float* src = wout + (size_t)(mt * 16 + r) * DOUT + kt * 32 + q * 8;
        short8 h;
        #pragma unroll
        for (int j = 0; j < 8; ++j) h[j] = bf16rn(src[j]);
        *(short8*)&wof[(size_t)tid * 8] = h;
    }
}

// ---------------------------------------------------------------------------
// qkv_gemm R26: main loop converted from the R13-era 2-barrier single-buffer
// (8 its x BK=64, DMA latency exposed each it) to the proven 1-barrier
// double-buffered pinned-drain protocol (attn R16-R24, out_gemm): BK=32 per
// buffer, 2 x 24 KB = 48 KB (same pool, same 3 blocks/CU), 16 K-steps, DMA
// for step t+1 lands under step t's compute.  Barrier count unchanged (16);
// latency exposure removed.  Epilogue (Cs alias + frag emission) unchanged;
// pinned drain added before pool reuse (trap #18 applies to other waves'
// in-flight ds_reads vs our Cs ds_writes).
// ---------------------------------------------------------------------------
__global__ __launch_bounds__(256) void qkv_gemm(const short* __restrict__ xhi,
                                                const short* __restrict__ xlo,
                                                const short* __restrict__ whi,
                                                const short* __restrict__ wlo,
                                                short* __restrict__ khi,
                                                short* __restrict__ klo,
                                                short* __restrict__ vf,
                                                short* __restrict__ qhi,
                                                short* __restrict__ qlo) {
    __shared__ __align__(16) char pool[49152];
    // per buffer (12288 shorts = 24 KB): Ah [0,4096), Al [4096,8192),
    // Bh [8192,10240), Bl [10240,12288)
    short* S = (short*)pool;
    float (*Cs)[65] = (float(*)[65])pool;   // 128*65*4 = 33280 B (alias)

    // XCD swizzle: idx = (g&7) + 8*((g>>3)*10 + cb), g = M-tile id [0,64)
    const int idx = blockIdx.x;
    const int low = idx & 7, rest = idx >> 3;
    const int cb = rest % 10, gh = rest / 10;
    const int g = gh * 8 + low;
    const int b = g >> 3, bml = g & 7;      // rows n0 = bml*128

    const int tid = threadIdx.x, w = tid >> 6, lane = tid & 63;
    const int q = lane >> 4, r = lane & 15;
    f32x4 acc[2][4];
    #pragma unroll
    for (int i = 0; i < 2; ++i)
        #pragma unroll
        for (int j = 0; j < 4; ++j) acc[i][j] = (f32x4){0.f, 0.f, 0.f, 0.f};

    // stage one BK=32 k-step kt_ into buffer buf_: per wave 6 dma16
    // (A rowtiles w and w+4, hi+lo; B coltile w, hi+lo).
    #define QSTAGE(kt_, buf_) {                                                  \
        short* dst_ = S + (buf_) * 12288;                                        \
        _Pragma("unroll")                                                        \
        for (int u0_ = 0; u0_ < 2; ++u0_) {                                      \
            int rowt_ = w + u0_ * 4;                                             \
            size_t ga_ = ((size_t)((b * 64 + bml * 8 + rowt_) * 16 + (kt_))) * 512 + lane * 8; \
            dma16(xhi + ga_, dst_ + rowt_ * 512);                                \
            dma16(xlo + ga_, dst_ + 4096 + rowt_ * 512);                         \
        }                                                                        \
        size_t gb_ = ((size_t)((cb * 4 + w) * 16 + (kt_))) * 512 + lane * 8;     \
        dma16(whi + gb_, dst_ + 8192 + w * 512);                                 \
        dma16(wlo + gb_, dst_ + 10240 + w * 512);                                \
    }

    QSTAGE(0, 0);

    for (int t = 0; t < 16; ++t) {
        const int cur = t & 1;
        // pinned drain (proven protocol): own DMA for buf[cur] landed (vmcnt)
        // + own ds_reads of buf[cur^1] retired (lgkm), then barrier.
        __builtin_amdgcn_sched_barrier(0);
        asm volatile("s_waitcnt vmcnt(0) lgkmcnt(0)" ::: "memory");
        __builtin_amdgcn_sched_barrier(0);
        __syncthreads();
        if (t < 15) QSTAGE(t + 1, cur ^ 1);

        const short* S0 = S + cur * 12288;
        short8 ah[2], al[2];
        #pragma unroll
        for (int rt = 0; rt < 2; ++rt) {
            ah[rt] = *(short8*)&S0[(w * 2 + rt) * 512 + lane * 8];
            al[rt] = *(short8*)&S0[4096 + (w * 2 + rt) * 512 + lane * 8];
        }
        #pragma unroll
        for (int tt = 0; tt < 4; ++tt) {
            short8 bh = *(short8*)&S0[8192 + tt * 512 + lane * 8];
            short8 bl = *(short8*)&S0[10240 + tt * 512 + lane * 8];
            #pragma unroll
            for (int rt = 0; rt < 2; ++rt) {
                acc[rt][tt] = __builtin_amdgcn_mfma_f32_16x16x32_bf16(ah[rt], bh, acc[rt][tt], 0, 0, 0);
                acc[rt][tt] = __builtin_amdgcn_mfma_f32_16x16x32_bf16(ah[rt], bl, acc[rt][tt], 0, 0, 0);
                acc[rt][tt] = __builtin_amdgcn_mfma_f32_16x16x32_bf16(al[rt], bh, acc[rt][tt], 0, 0, 0);
            }
        }
    }
    #undef QSTAGE

    // ---- fused epilogue: C tile (128x64) -> LDS -> frag-order bf16 global ----
    // drain before pool reuse: other waves' in-flight ds_reads of S must
    // retire before our Cs ds_writes land (trap #18; no DMA outstanding).
    __builtin_amdgcn_sched_barrier(0);
    asm volatile("s_waitcnt vmcnt(0) lgkmcnt(0)" ::: "memory");
    __builtin_amdgcn_sched_barrier(0);
    __syncthreads();
    #pragma unroll
    for (int rt = 0; rt < 2; ++rt)
        #pragma unroll
        for (int reg = 0; reg < 4; ++reg)
            #pragma unroll
            for (int tt = 0; tt < 4; ++tt)
                Cs[w * 32 + rt * 16 + q * 4 + reg][tt * 16 + r] = acc[rt][tt][reg];
    __syncthreads();

    if (cb == 0) {
        // K: 2 t-tiles; elem K[m=t*64+i*16+r2][kd=cc*32+q2*8+j], ic=i*2+cc
        for (int u = tid; u < 1024; u += 256) {
            int lane2 = u & 63, ic = (u >> 6) & 7, tl = u >> 9;
            int q2 = lane2 >> 4, r2 = lane2 & 15;
            int i = ic >> 1, cc = ic & 1;
            short8 h8, l8;
            #pragma unroll
            for (int j = 0; j < 8; ++j) {
                HL s = bf16split(Cs[tl * 64 + i * 16 + r2][cc * 32 + q2 * 8 + j]);
                h8[j] = s.h; l8[j] = s.l;
            }
            size_t off = ((size_t)(b * 16 + bml * 2 + tl) * 8 + ic) * 512 + lane2 * 8;
            *(short8*)&khi[off] = h8;
            *(short8*)&klo[off] = l8;
        }
    } else if (cb == 1) {
        // V (R20): 16x16x16 B-frag order.  ic = c4*4+tv; element
        // V[key = tl*64 + c4*16 + qn*4 + j][v = tv*16 + r].
        for (int u = tid; u < 1024; u += 256) {
            int a = u & 31, ic = (u >> 5) & 15, tl = u >> 9;
            int c4 = ic >> 2, tv = ic & 3;
            short8 v8;
            #pragma unroll
            for (int jj = 0; jj < 8; ++jj) {
                int lane2 = a * 2 + (jj >> 2), j = jj & 3;
                int qn = lane2 >> 4, r2 = lane2 & 15;
                v8[jj] = bf16rn(Cs[tl * 64 + c4 * 16 + qn * 4 + j][tv * 16 + r2]);
            }
            size_t off = ((size_t)(b * 16 + bml * 2 + tl) * 16 + ic) * 256 + a * 8;
            *(short8*)&vf[off] = v8;
        }
    } else {
        // Q head hd: 8 nt-tiles x 2 kc = 16 chunks
        const int hd = cb - 2;
        const float qscale = 0.125f * 1.44269504f;
        for (int u = tid; u < 1024; u += 256) {
            int lane2 = u & 63, ch = u >> 6;        // ch in [0,16)
            int q2 = lane2 >> 4, r2 = lane2 & 15;
            int kc = ch & 1, ntl = ch >> 1;         // ntl in [0,8)
            short8 h8, l8;
            #pragma unroll
            for (int j = 0; j < 8; ++j) {
                HL s = bf16split(Cs[ntl * 16 + r2][kc * 32 + q2 * 8 + j] * qscale);
                h8[j] = s.h; l8[j] = s.l;
            }
            size_t off = ((((size_t)(b * 8 + hd) * 64 + bml * 8 + ntl) * 2 + kc) * 64 + lane2) * 8;
            *(short8*)&qhi[off] = h8;
            *(short8*)&qlo[off] = l8;
        }
    }
}

// ---------------------------------------------------------------------------
// attn: R24 structure, FROZEN (measured 52.7 µs, conflicts 0, MfmaUtil 35%,
// Occ 34% — prediction matched; all restructures R18/R20/R22 lost).
// = R19 (8 waves x 1 q-tile, 64-key tiles, register-P swapped QK^T,
// 1 barrier/tile pinned-drain dbuf staging) + R20 conflict-free V layout.
// ---------------------------------------------------------------------------
__global__ __launch_bounds__(512) void attn_mfma(const short* __restrict__ qhi_g,
                                                 const short* __restrict__ qlo_g,
                                                 const short* __restrict__ khi_g,
                                                 const short* __restrict__ klo_g,
                                                 const short* __restrict__ vf_g,
                                                 short* __restrict__ ob) {
    __shared__ short Khi[2][4096], Klo[2][4096], Vf[2][4096];   // 48 KB
    const int blk = blockIdx.x;
    const int b   = blk & 7;        // XCD = blk%8 = b -> per-XCD K/V L2 locality
    const int h   = (blk >> 3) & 7;
    const int qt  = blk >> 6;
    const int tid = threadIdx.x;
    const int w    = tid >> 6;      // 8 waves
    const int lane = tid & 63;
    const int q    = lane >> 4;
    const int r    = lane & 15;
    const int nt = qt * 8 + w;      // this wave's 16-row q-tile

    short8 qhi[2], qlo[2];
    #pragma unroll
    for (int c = 0; c < 2; ++c) {
        size_t off = ((((size_t)(b * 8 + h) * 64 + nt) * 2 + c) * 64 + lane) * 8;
        qhi[c] = *(const short8*)&qhi_g[off];
        qlo[c] = *(const short8*)&qlo_g[off];
    }

    short4v bones4;
    #pragma unroll
    for (int j = 0; j < 4; ++j) bones4[j] = (short)0x3F80;

    f32x4 oacc[4], lacc;
    #pragma unroll
    for (int tt = 0; tt < 4; ++tt) oacc[tt] = (f32x4){0.f, 0.f, 0.f, 0.f};
    lacc = (f32x4){0.f, 0.f, 0.f, 0.f};
    float m_ = -1e30f;              // running row-max (row = r), log2 space

    const int kbase = lane * 8;     // K frag base (shorts)
    const int vbase = lane * 4;     // V frag base (shorts) — lane-contiguous

    // prologue: DMA tile 0 into buffer 0 (each wave stages chunk ch = w)
    {
        const size_t kb = ((size_t)(b * 16 + 0) * 8) * 512;
        dma16(khi_g + kb + w * 512 + lane * 8, &Khi[0][w * 512]);
        dma16(klo_g + kb + w * 512 + lane * 8, &Klo[0][w * 512]);
        dma16(vf_g  + kb + w * 512 + lane * 8, &Vf [0][w * 512]);
    }

    for (int t = 0; t < 16; ++t) {
        const int cur = t & 1;
        // pinned drain: own DMA landed (vmcnt) AND own ds_reads retired (lgkm)
        // before the barrier; closes the trap-#18 race (proven R16-R24).
        __builtin_amdgcn_sched_barrier(0);
        asm volatile("s_waitcnt vmcnt(0) lgkmcnt(0)" ::: "memory");
        __builtin_amdgcn_sched_barrier(0);
        __syncthreads();
        if (t < 15) {               // issue next tile into buf[cur^1]
            const size_t kb = ((size_t)(b * 16 + t + 1) * 8) * 512;
            dma16(khi_g + kb + w * 512 + lane * 8, &Khi[cur ^ 1][w * 512]);
            dma16(klo_g + kb + w * 512 + lane * 8, &Klo[cur ^ 1][w * 512]);
            dma16(vf_g  + kb + w * 512 + lane * 8, &Vf [cur ^ 1][w * 512]);
        }

        // ---- swapped QK^T: sT[i] lane(q,r) reg: S[key=i*16+q*4+reg][row=r]
        //      (split-bf16 3-term) ----
        f32x4 sT[4];
        #pragma unroll
        for (int i = 0; i < 4; ++i) sT[i] = (f32x4){0.f, 0.f, 0.f, 0.f};
        #pragma unroll
        for (int cc = 0; cc < 2; ++cc) {
            #pragma unroll
            for (int i = 0; i < 4; ++i) {
                short8 kh = *(short8*)&Khi[cur][(i * 2 + cc) * 512 + kbase];
                short8 kl = *(short8*)&Klo[cur][(i * 2 + cc) * 512 + kbase];
                sT[i] = __builtin_amdgcn_mfma_f32_16x16x32_bf16(kh, qhi[cc], sT[i], 0, 0, 0);
                sT[i] = __builtin_amdgcn_mfma_f32_16x16x32_bf16(kl, qhi[cc], sT[i], 0, 0, 0);
                sT[i] = __builtin_amdgcn_mfma_f32_16x16x32_bf16(kh, qlo[cc], sT[i], 0, 0, 0);
            }
        }

        // ---- lazy online softmax (log2 space; m_ scalar per lane = row r) ----
        float pm;
        {
            float a0 = fmaxf(fmaxf(sT[0][0], sT[0][1]), fmaxf(sT[0][2], sT[0][3]));
            float a1 = fmaxf(fmaxf(sT[1][0], sT[1][1]), fmaxf(sT[1][2], sT[1][3]));
            float a2 = fmaxf(fmaxf(sT[2][0], sT[2][1]), fmaxf(sT[2][2], sT[2][3]));
            float a3 = fmaxf(fmaxf(sT[3][0], sT[3][1]), fmaxf(sT[3][2], sT[3][3]));
            pm = fmaxf(fmaxf(a0, a1), fmaxf(a2, a3));
        }
        bool need = (pm > m_ + 30.f);
        if (__any((int)need)) {
            // full row max across the 4 q-lanes of row r
            float full = fmaxf(pm, __shfl_xor(pm, 16));
            full = fmaxf(full, __shfl_xor(full, 32));
            float nm = fmaxf(m_, full);
            float alpha = exp2f(m_ - nm);
            m_ = nm;
            // redistribute alpha to oacc/lacc rows (row q*4+reg lives at
            // lane with r' = q*4+reg; pick source lane q*16 + q*4 + reg)
            #pragma unroll
            for (int reg = 0; reg < 4; ++reg) {
                float areg = __shfl(alpha, q * 20 + reg);
                lacc[reg] *= areg;
                #pragma unroll
                for (int tt = 0; tt < 4; ++tt) oacc[tt][reg] *= areg;
            }
        }
        #pragma unroll
        for (int i = 0; i < 4; ++i)
            #pragma unroll
            for (int reg = 0; reg < 4; ++reg)
                sT[i][reg] = exp2f(sT[i][reg] - m_);

        // ---- PV: zero-shuffle register P (16x16x16 A-frag); V frags
        //      lane-contiguous b64 (conflict-free) ----
        #pragma unroll
        for (int c = 0; c < 4; ++c) {
            union { uint2 u; short4v s; } pk;
            pk.u.x = packbf2(sT[c][0], sT[c][1]);
            pk.u.y = packbf2(sT[c][2], sT[c][3]);
            short4v pf = pk.s;
            lacc = mfma16(pf, bones4, lacc);
            #pragma unroll
            for (int tt = 0; tt < 4; ++tt) {
                short4v vfr = *(const short4v*)&Vf[cur][(c * 4 + tt) * 256 + vbase];
                oacc[tt] = mfma16(pf, vfr, oacc[tt]);
            }
        }
    }

    // hazard guard for the inline-asm MFMA fallback (MFMA write -> VALU read)
    asm volatile("s_nop 7\n\ts_nop 7" :::);

    // ---- epilogue: O frag-order bf16 store (D layout unchanged) ----
    #pragma unroll
    for (int reg = 0; reg < 4; ++reg) {
        float inv = 1.f / lacc[reg];
        #pragma unroll
        for (int tt = 0; tt < 4; ++tt) {
            int ct = h * 2 + (tt >> 1);
            int lanep = ((tt & 1) * 2 + (r >> 3)) * 16 + q * 4 + reg;
            ob[((((size_t)b * 64 + nt) * 16 + ct) * 64 + lanep) * 8 + (r & 7)] =
                bf16rn(oacc[tt][reg] * inv);
        }
    }
}

// ---------------------------------------------------------------------------
// out_gemm: plain bf16 MFMA, double-buffered staging (unchanged).
// ---------------------------------------------------------------------------
__global__ __launch_bounds__(256) void out_gemm(const short* __restrict__ wof,
                                                const short* __restrict__ obf,
                                                float* __restrict__ out) {
    __shared__ short Ah[2][4096];
    __shared__ short Bh[2][4096];
    const int b = blockIdx.z, bd = blockIdx.y, bn = blockIdx.x;
    const int tid = threadIdx.x, w = tid >> 6, lane = tid & 63;
    const int q = lane >> 4, r = lane & 15;
    f32x4 acc[4];
    #pragma unroll
    for (int j = 0; j < 4; ++j) acc[j] = (f32x4){0.f, 0.f, 0.f, 0.f};

    for (int u = w; u < 8; u += 4) {
        size_t ga = ((size_t)((bd * 4 + (u >> 1)) * 16 + (u & 1))) * 512 + lane * 8;
        dma16(wof + ga, &Ah[0][u * 512]);
        size_t gb = ((size_t)((b * 64 + bn * 4 + (u >> 1)) * 16 + (u & 1))) * 512 + lane * 8;
        dma16(obf + gb, &Bh[0][u * 512]);
    }

    for (int it = 0; it < 8; ++it) {
        const int cur = it & 1;
        __syncthreads();
        if (it < 7) {
            for (int u = w; u < 8; u += 4) {
                size_t ga = ((size_t)((bd * 4 + (u >> 1)) * 16 + (it + 1) * 2 + (u & 1))) * 512 + lane * 8;
                dma16(wof + ga, &Ah[cur ^ 1][u * 512]);
                size_t gb = ((size_t)((b * 64 + bn * 4 + (u >> 1)) * 16 + (it + 1) * 2 + (u & 1))) * 512 + lane * 8;
                dma16(obf + gb, &Bh[cur ^ 1][u * 512]);
            }
        }
        #pragma unroll
        for (int kc = 0; kc < 2; ++kc) {
            short8 a = *(short8*)&Ah[cur][(w * 2 + kc) * 512 + lane * 8];
            #pragma unroll
            for (int tt = 0; tt < 4; ++tt) {
                short8 bb = *(short8*)&Bh[cur][(tt * 2 + kc) * 512 + lane * 8];
                acc[tt] = __builtin_amdgcn_mfma_f32_16x16x32_bf16(a, bb, acc[tt], 0, 0, 0);
            }
        }
    }
    const int d_base = bd * 64 + w * 16;
    #pragma unroll
    for (int reg = 0; reg < 4; ++reg)
        #pragma unroll
        for (int tt = 0; tt < 4; ++tt)
            out[((size_t)b * DOUT + d_base + q * 4 + reg) * NTOK
                + bn * 64 + tt * 16 + r] = acc[tt][reg];
}

// ---------------------------------------------------------------------------
extern "C" void kernel_launch(void* const* d_in, const int* in_sizes, int n_in,
                              void* d_out, int out_size, void* d_ws, size_t ws_size,
                              hipStream_t stream) {
    const float* x  = (const float*)d_in[0];
    const float* qp = (const float*)d_in[1];
    const float* kp = (const float*)d_in[2];
    const float* vp = (const float*)d_in[3];
    const float* op = (const float*)d_in[4];
    float* out = (float*)d_out;

    // workspace: 38.5 MB (proven R12/R13)
    short* Whi = (short*)d_ws;                 // 327,680
    short* Wlo = Whi + 327680;                 // 327,680
    short* Xhi = Wlo + 327680;                 // 4,194,304
    short* Xlo = Xhi + 4194304;                // 4,194,304
    short* Qhi = Xlo + 4194304;                // 4,194,304
    short* Qlo = Qhi + 4194304;                // 4,194,304
    short* Khi = Qlo + 4194304;                // 524,288
    short* Klo = Khi + 524288;                 // 524,288
    short* Vf  = Klo + 524288;                 // 524,288
    short* Wof = Vf  + 524288;                 // 262,144
    short* Ob  = Xhi;                          // alias: X dead after qkv_gemm

    prepack_all <<<1312, 256, 0, stream>>>(x, qp, kp, vp, op,
                                           Whi, Wlo, Xhi, Xlo, Wof);
    qkv_gemm    <<<640, 256, 0, stream>>>(Xhi, Xlo, Whi, Wlo,
                                          Khi, Klo, Vf, Qhi, Qlo);
    attn_mfma   <<<512, 512, 0, stream>>>(Qhi, Qlo, Khi, Klo, Vf, Ob);
    out_gemm    <<<dim3(16, 8, BATCH), 256, 0, stream>>>(Wof, Ob, out);
}